// Round 11
// baseline (492.085 us; speedup 1.0000x reference)
//
#include <hip/hip_runtime.h>
#include <cmath>

#define NNODES 60000
#define DDIM   200
#define NCLS   250

constexpr int R   = 64;        // rows per block -> 938 blocks (32-row tail)
constexpr int BK  = 32;        // K per MFMA step
constexpr int XP  = 232;       // act pitch (shorts): 464B, 16B-aligned, 2-way banks

// LDS arena (shorts): X | H | a_sw(2x2048) | w_sw(2x8192)
constexpr int O_X  = 0;
constexpr int O_H  = R * XP;                 // 14848
constexpr int O_A  = 2 * R * XP;             // 29696
constexpr int AS   = R * BK;                 // 2048 shorts per a buf (4KB)
constexpr int O_W  = O_A + 2 * AS;           // 33792
constexpr int WS   = 8192;                   // shorts per w buf (16KB)
constexpr int SH_TOT = O_W + 2 * WS + 32;    // 50208 shorts = 100.4KB

typedef float  f32x4  __attribute__((ext_vector_type(4)));
typedef short  short8 __attribute__((ext_vector_type(8)));

// ---- ws layout (R3-verified): W_P1 [256][608]; 11 mats [256][224]
constexpr int W_P1  = 0;
constexpr int W_P2A = 155648;
constexpr int W_P2B = 212992;
constexpr int W_FX  = 270336;
constexpr int W_FH  = 327680;
constexpr int W_IX  = 385024;
constexpr int W_IH  = 442368;
constexpr int W_UX  = 499712;
constexpr int W_UH  = 557056;
constexpr int W_OX  = 614400;
constexpr int W_OH  = 671744;
constexpr int W_FC2 = 729088;
constexpr int W_TOTAL_ELEMS = 786432;
constexpr size_t W_TOTAL_BYTES = (size_t)W_TOTAL_ELEMS * 2;

__device__ __forceinline__ short f2b(float f) {
    union { float f; unsigned u; } x; x.f = f;
    unsigned r = (x.u + 0x7FFFu + ((x.u >> 16) & 1u)) >> 16;   // RNE
    return (short)r;
}
__device__ __forceinline__ unsigned cvtpk(float lo, float hi) {
    unsigned r; asm("v_cvt_pk_bf16_f32 %0, %1, %2" : "=v"(r) : "v"(lo), "v"(hi));
    return r;
}
__device__ __forceinline__ short f2b1(float f) { return (short)(cvtpk(f, f) & 0xffffu); }
__device__ __forceinline__ float b2f(short s) {
    union { unsigned u; float f; } x; x.u = ((unsigned)(unsigned short)s) << 16;
    return x.f;
}
__device__ __forceinline__ float b2f_lo(unsigned u) { return b2f((short)(u & 0xffffu)); }
__device__ __forceinline__ float b2f_hi(unsigned u) { return b2f((short)(u >> 16)); }
__device__ __forceinline__ float sgm(float x)  { return 1.0f / (1.0f + __expf(-x)); }
__device__ __forceinline__ float tanh_fast(float x) { return 1.0f - 2.0f / (__expf(2.0f * x) + 1.0f); }
__device__ __forceinline__ int   swz(int b)    { return b ^ (((b >> 7) & 3) << 4); }
__device__ __forceinline__ short8 cvt8(float4 f0, float4 f1) {
    union { unsigned u[4]; short8 s; } c;
    c.u[0] = cvtpk(f0.x, f0.y); c.u[1] = cvtpk(f0.z, f0.w);
    c.u[2] = cvtpk(f1.x, f1.y); c.u[3] = cvtpk(f1.z, f1.w);
    return c.s;
}

// ================= weight prepass (R3 verbatim — verified) =================
__global__ void wprep(const float* __restrict__ p1w, const float* __restrict__ p2w,
                      const float* __restrict__ fxw, const float* __restrict__ fhw,
                      const float* __restrict__ ixw, const float* __restrict__ ihw,
                      const float* __restrict__ uxw, const float* __restrict__ uhw,
                      const float* __restrict__ oxw, const float* __restrict__ ohw,
                      const float* __restrict__ fc2w, short* __restrict__ ws)
{
    int i = blockIdx.x * 256 + threadIdx.x;
    if (i >= W_TOTAL_ELEMS) return;
    float v = 0.0f;
    if (i < W_P2A) {                       // p1: [256][608], src 200x600
        int n = i / 608, k = i % 608;
        if (n < 200 && k < 600) v = p1w[n * 600 + k];
        ws[i] = f2b(v); return;
    }
    int j = i - W_P2A;
    int m = j / 57344, rem = j % 57344;
    int n = rem / 224, k = rem % 224;
    const float* src; int stride = 200, off = 0, ncols = 200;
    switch (m) {
        case 0:  src = p2w; stride = 400; break;
        case 1:  src = p2w; stride = 400; off = 200; break;
        case 2:  src = fxw; break;
        case 3:  src = fhw; break;
        case 4:  src = ixw; break;
        case 5:  src = ihw; break;
        case 6:  src = uxw; break;
        case 7:  src = uhw; break;
        case 8:  src = oxw; break;
        case 9:  src = ohw; break;
        default: src = fc2w; ncols = 250; break;
    }
    if (n < ncols && k < 200) v = src[n * stride + off + k];
    ws[i] = f2b(v);
}

// ================= staging (R3-verified addressing; q-stride 8 for 8 waves) =================
__device__ __forceinline__ void gload16(const void* g, void* l) {
    __builtin_amdgcn_global_load_lds((const __attribute__((address_space(1))) unsigned*)g,
                                     (__attribute__((address_space(3))) unsigned*)l, 16, 0, 0);
}

__device__ __forceinline__ void stage_w(const short* __restrict__ wmat, int Kpad, int t,
                                        int wrows, int wv, short* w_sw)
{
    const int issues = wrows >> 4;               // 1KB per issue
    for (int q = wv; q < issues; q += 8) {
        const int lane = threadIdx.x & 63;
        const int db = q * 1024 + lane * 16;     // linear dest byte
        const int n  = db >> 6;
        const int g  = (db >> 4) & 3;
        const int gs = g ^ ((n >> 1) & 3);       // inverse swizzle on source
        const short* src = wmat + (long)n * Kpad + t * BK + gs * 8;
        char* dst = ((char*)w_sw) + q * 1024;
        gload16(src, dst);
    }
}

__device__ __forceinline__ void stage_a_chh(short* a_sw, const float* __restrict__ ag,
                                            int row0, int colofs, int k0, int Kreal, int tid)
{
    if (tid >= 4 * R) return;                    // 256 workers: 64 rows x 4 chunks
    const int r = tid >> 2, gq = tid & 3;
    long rg = row0 + r; if (rg >= NNODES) rg = NNODES - 1;   // tail clamp
    const float* src = ag + rg * 800 + colofs + k0 + gq * 8;
    short8 v;
    if (k0 + BK <= Kreal) {
        float4 f0 = *(const float4*)(src);
        float4 f1 = *(const float4*)(src + 4);
        v = cvt8(f0, f1);
    } else {
        #pragma unroll
        for (int i = 0; i < 8; ++i) {
            int k = k0 + gq * 8 + i;
            float f = (k < Kreal) ? src[i] : 0.0f;
            v[i] = f2b(f);
        }
    }
    int b = r * 64 + gq * 16; b = swz(b);
    *(short8*)((char*)a_sw + b) = v;
}

// ================= GEMM pass: dbuf, stage(t+1) issued BEFORE compute(t) =================
template<int NF, bool FROM_GLOBAL>
__device__ __forceinline__ void gemm_pass(
    f32x4 (&acc)[2][NF],
    const short* __restrict__ Ap,                // act base (LA), pitch XP
    const float* __restrict__ ag, int row0, int colofs, int Kreal,
    const short* __restrict__ wmat, int ktiles, int Kpad, int wrows,
    short* a_sw, short* w_sw,
    int tid, int wv, int wm, int wn, int l15, int lg)
{
    stage_w(wmat, Kpad, 0, wrows, wv, w_sw);
    if constexpr (FROM_GLOBAL)
        stage_a_chh(a_sw, ag, row0, colofs, 0, Kreal, tid);
    __syncthreads();                             // drain + barrier: tile 0 visible
    for (int t = 0; t < ktiles; ++t) {
        const int cur = t & 1, nxt = cur ^ 1;
        if (t + 1 < ktiles) {                    // issue next-tile stage BEFORE compute
            stage_w(wmat, Kpad, t + 1, wrows, wv, w_sw + nxt * WS);
            if constexpr (FROM_GLOBAL)
                stage_a_chh(a_sw + nxt * AS, ag, row0, colofs, (t + 1) * BK, Kreal, tid);
        }
        short8 af[2];
        #pragma unroll
        for (int mi = 0; mi < 2; ++mi) {
            const int row = wm * 32 + mi * 16 + l15;
            if constexpr (FROM_GLOBAL)
                af[mi] = *(const short8*)((const char*)(a_sw + cur * AS) + swz(row * 64 + lg * 16));
            else
                af[mi] = *(const short8*)(Ap + row * XP + t * BK + lg * 8);
        }
        #pragma unroll
        for (int ni = 0; ni < NF; ++ni) {
            const int n = (wn * NF + ni) * 16 + l15;
            short8 bf = *(const short8*)((const char*)(w_sw + cur * WS) + swz(n * 64 + lg * 16));
            acc[0][ni] = __builtin_amdgcn_mfma_f32_16x16x32_bf16(af[0], bf, acc[0][ni], 0, 0, 0);
            acc[1][ni] = __builtin_amdgcn_mfma_f32_16x16x32_bf16(af[1], bf, acc[1][ni], 0, 0, 0);
        }
        __syncthreads();                         // drain(next stage) + barrier: swap safe
    }
}

#define Z24(A)  { _Pragma("unroll") for (int m_=0;m_<2;++m_) { _Pragma("unroll") for (int z_=0; z_<4; ++z_) { _Pragma("unroll") for (int q_=0;q_<4;++q_) A[m_][z_][q_] = 0.0f; } } }

__global__ __launch_bounds__(512, 1)
void fused_v8(const int* __restrict__ tok,
              const float* __restrict__ chc,
              const float* __restrict__ chh,
              const float* __restrict__ emb,
              const float* __restrict__ p1b_, const float* __restrict__ p2b_,
              const float* __restrict__ ixb, const float* __restrict__ ihb,
              const float* __restrict__ fxb, const float* __restrict__ fhb,
              const float* __restrict__ uxb, const float* __restrict__ uhb,
              const float* __restrict__ oxb, const float* __restrict__ ohb,
              const float* __restrict__ fc2b,
              const short* __restrict__ ws,
              float* __restrict__ out)
{
    __shared__ __align__(16) short SH[SH_TOT];
    short* X    = SH + O_X;      // x
    short* H    = SH + O_H;      // control -> hs -> h
    short* a_sw = SH + O_A;      // 2 x 4KB
    short* w_sw = SH + O_W;      // 2 x 16KB

    const int tid = threadIdx.x;
    const int wv  = tid >> 6;                // 0..7
    const int wm  = wv >> 2;                 // 0..1 (rows)
    const int wn  = wv & 3;                  // 0..3 (cols, NF=4)
    const int l15 = tid & 15, lg = (tid & 63) >> 4;
    const int row0 = blockIdx.x * R;

    // ---- zero arena pads, stage x ----
    {
        short8 z = (short8)0;
        short8* shv = (short8*)SH;
        #pragma unroll 1
        for (int i = tid; i < SH_TOT / 8; i += 512) shv[i] = z;
    }
    __syncthreads();
    {
        #pragma unroll 1
        for (int u = tid; u < 1600; u += 512) {  // 64 rows x 25 chunks of 8 cols
            int r = u / 25, cu = (u % 25) * 8;
            long rg = row0 + r; if (rg >= NNODES) rg = NNODES - 1;
            const float* s = emb + (long)tok[rg] * DDIM + cu;
            float4 f0 = *(const float4*)s, f1 = *(const float4*)(s + 4);
            *(short8*)(X + r * XP + cu) = cvt8(f0, f1);
        }
    }
    __syncthreads();

    f32x4 g[2][4];

    // ==== P1: control = relu([ch0|ch1|ch2] @ p1^T + b) -> H ====
    Z24(g);
    gemm_pass<4, true>(g, nullptr, chh, row0, 0, 600, ws + W_P1, 19, 608, 224,
                       a_sw, w_sw, tid, wv, wm, wn, l15, lg);
    #pragma unroll
    for (int mi = 0; mi < 2; ++mi)
        #pragma unroll
        for (int ni = 0; ni < 4; ++ni) {
            const int col = (wn * 4 + ni) * 16 + l15;
            if (col < DDIM) {
                const float b = p1b_[col];
                #pragma unroll
                for (int j = 0; j < 4; ++j) {
                    const int lr = wm * 32 + mi * 16 + lg * 4 + j;
                    H[lr * XP + col] = f2b1(fmaxf(g[mi][ni][j] + b, 0.0f));
                }
            }
        }
    // (next pass prologue __syncthreads publishes H)

    // ==== P2: hs = relu(control@p2a^T + ch3@p2b^T + b) -> H ====
    Z24(g);
    gemm_pass<4, false>(g, H, nullptr, 0, 0, 0, ws + W_P2A, 7, 224, 224,
                        a_sw, w_sw, tid, wv, wm, wn, l15, lg);
    gemm_pass<4, true>(g, nullptr, chh, row0, 600, 200, ws + W_P2B, 7, 224, 224,
                       a_sw, w_sw, tid, wv, wm, wn, l15, lg);
    #pragma unroll
    for (int mi = 0; mi < 2; ++mi)
        #pragma unroll
        for (int ni = 0; ni < 4; ++ni) {
            const int col = (wn * 4 + ni) * 16 + l15;
            if (col < DDIM) {
                const float b = p2b_[col];
                #pragma unroll
                for (int j = 0; j < 4; ++j) {
                    const int lr = wm * 32 + mi * 16 + lg * 4 + j;
                    H[lr * XP + col] = f2b1(fmaxf(g[mi][ni][j] + b, 0.0f));
                }
            }
        }

    // ==== I gate -> gi packed ====
    unsigned gi[2][4][2];
    Z24(g);
    gemm_pass<4, false>(g, X, nullptr, 0, 0, 0, ws + W_IX, 7, 224, 224,
                        a_sw, w_sw, tid, wv, wm, wn, l15, lg);
    gemm_pass<4, false>(g, H, nullptr, 0, 0, 0, ws + W_IH, 7, 224, 224,
                        a_sw, w_sw, tid, wv, wm, wn, l15, lg);
    #pragma unroll
    for (int mi = 0; mi < 2; ++mi)
        #pragma unroll
        for (int ni = 0; ni < 4; ++ni) {
            const int col = (wn * 4 + ni) * 16 + l15;
            const float b = (col < DDIM) ? (ixb[col] + ihb[col]) : 0.0f;
            gi[mi][ni][0] = cvtpk(sgm(g[mi][ni][0] + b), sgm(g[mi][ni][1] + b));
            gi[mi][ni][1] = cvtpk(sgm(g[mi][ni][2] + b), sgm(g[mi][ni][3] + b));
        }

    // ==== U gate -> iu = i*tanh(u) packed ====
    unsigned iu[2][4][2];
    Z24(g);
    gemm_pass<4, false>(g, X, nullptr, 0, 0, 0, ws + W_UX, 7, 224, 224,
                        a_sw, w_sw, tid, wv, wm, wn, l15, lg);
    gemm_pass<4, false>(g, H, nullptr, 0, 0, 0, ws + W_UH, 7, 224, 224,
                        a_sw, w_sw, tid, wv, wm, wn, l15, lg);
    #pragma unroll
    for (int mi = 0; mi < 2; ++mi)
        #pragma unroll
        for (int ni = 0; ni < 4; ++ni) {
            const int col = (wn * 4 + ni) * 16 + l15;
            const float b = (col < DDIM) ? (uxb[col] + uhb[col]) : 0.0f;
            float v0 = b2f_lo(gi[mi][ni][0]) * tanh_fast(g[mi][ni][0] + b);
            float v1 = b2f_hi(gi[mi][ni][0]) * tanh_fast(g[mi][ni][1] + b);
            float v2 = b2f_lo(gi[mi][ni][1]) * tanh_fast(g[mi][ni][2] + b);
            float v3 = b2f_hi(gi[mi][ni][1]) * tanh_fast(g[mi][ni][3] + b);
            iu[mi][ni][0] = cvtpk(v0, v1);
            iu[mi][ni][1] = cvtpk(v2, v3);
        }

    // ==== O gate -> o = sgm(o) packed ====
    unsigned og[2][4][2];
    Z24(g);
    gemm_pass<4, false>(g, X, nullptr, 0, 0, 0, ws + W_OX, 7, 224, 224,
                        a_sw, w_sw, tid, wv, wm, wn, l15, lg);
    gemm_pass<4, false>(g, H, nullptr, 0, 0, 0, ws + W_OH, 7, 224, 224,
                        a_sw, w_sw, tid, wv, wm, wn, l15, lg);
    #pragma unroll
    for (int mi = 0; mi < 2; ++mi)
        #pragma unroll
        for (int ni = 0; ni < 4; ++ni) {
            const int col = (wn * 4 + ni) * 16 + l15;
            const float b = (col < DDIM) ? (oxb[col] + ohb[col]) : 0.0f;
            og[mi][ni][0] = cvtpk(sgm(g[mi][ni][0] + b), sgm(g[mi][ni][1] + b));
            og[mi][ni][1] = cvtpk(sgm(g[mi][ni][2] + b), sgm(g[mi][ni][3] + b));
        }

    // ==== FX -> fxr packed ====
    unsigned fxr[2][4][2];
    Z24(g);
    gemm_pass<4, false>(g, X, nullptr, 0, 0, 0, ws + W_FX, 7, 224, 224,
                        a_sw, w_sw, tid, wv, wm, wn, l15, lg);
    #pragma unroll
    for (int mi = 0; mi < 2; ++mi)
        #pragma unroll
        for (int ni = 0; ni < 4; ++ni) {
            const int col = (wn * 4 + ni) * 16 + l15;
            const float b = (col < DDIM) ? fxb[col] : 0.0f;
            fxr[mi][ni][0] = cvtpk(g[mi][ni][0] + b, g[mi][ni][1] + b);
            fxr[mi][ni][1] = cvtpk(g[mi][ni][2] + b, g[mi][ni][3] + b);
        }

    // ==== FH x4: csum = sum_c sgm(ch_c@fh^T + fhb + fx) * chc_c ====
    float csum[2][4][4];
    #pragma unroll
    for (int mi = 0; mi < 2; ++mi)
        #pragma unroll
        for (int ni = 0; ni < 4; ++ni)
            #pragma unroll
            for (int j = 0; j < 4; ++j) csum[mi][ni][j] = 0.0f;

    #pragma unroll 1
    for (int c = 0; c < 4; ++c) {
        Z24(g);
        gemm_pass<4, true>(g, nullptr, chh, row0, c * 200, 200, ws + W_FH, 7, 224, 224,
                           a_sw, w_sw, tid, wv, wm, wn, l15, lg);
        #pragma unroll
        for (int mi = 0; mi < 2; ++mi)
            #pragma unroll
            for (int ni = 0; ni < 4; ++ni) {
                const int col = (wn * 4 + ni) * 16 + l15;
                if (col < DDIM) {
                    const float fb = fhb[col];
                    #pragma unroll
                    for (int j = 0; j < 4; ++j) {
                        long rg = row0 + wm * 32 + mi * 16 + lg * 4 + j;
                        if (rg >= NNODES) rg = NNODES - 1;
                        const float cv = chc[rg * 800 + c * 200 + col];
                        const unsigned pk = fxr[mi][ni][j >> 1];
                        const float fx = (j & 1) ? b2f_hi(pk) : b2f_lo(pk);
                        csum[mi][ni][j] += sgm(g[mi][ni][j] + fb + fx) * cv;
                    }
                }
            }
    }

    // ==== c = iu + csum ; h = o*tanh(c) -> H (all same-thread cells) ====
    #pragma unroll
    for (int mi = 0; mi < 2; ++mi)
        #pragma unroll
        for (int ni = 0; ni < 4; ++ni) {
            const int col = (wn * 4 + ni) * 16 + l15;
            if (col < DDIM) {
                #pragma unroll
                for (int j = 0; j < 4; ++j) {
                    const int lr = wm * 32 + mi * 16 + lg * 4 + j;
                    const unsigned pi = iu[mi][ni][j >> 1];
                    const unsigned po = og[mi][ni][j >> 1];
                    const float iv = (j & 1) ? b2f_hi(pi) : b2f_lo(pi);
                    const float ov = (j & 1) ? b2f_hi(po) : b2f_lo(po);
                    H[lr * XP + col] = f2b1(ov * tanh_fast(iv + csum[mi][ni][j]));
                }
            }
        }
    // (FC2 pass prologue __syncthreads publishes H)

    // ==== FC2: logits = h @ fc2^T + b -> out ====
    Z24(g);
    gemm_pass<4, false>(g, H, nullptr, 0, 0, 0, ws + W_FC2, 7, 224, 256,
                        a_sw, w_sw, tid, wv, wm, wn, l15, lg);
    #pragma unroll
    for (int mi = 0; mi < 2; ++mi)
        #pragma unroll
        for (int ni = 0; ni < 4; ++ni) {
            const int col = (wn * 4 + ni) * 16 + l15;
            if (col < NCLS) {
                const float b = fc2b[col];
                #pragma unroll
                for (int j = 0; j < 4; ++j) {
                    const long gr = row0 + wm * 32 + mi * 16 + lg * 4 + j;
                    if (gr < NNODES) out[gr * NCLS + col] = g[mi][ni][j] + b;
                }
            }
        }
}

// ================= fallback fp32 kernel (used only if ws too small) =================
constexpr int FRT = 32, FBK = 16, FNT = 256, FRTP = FRT + 4, FBUFP = 208;
__device__ __forceinline__ float sgm_f(float x) { return 1.0f / (1.0f + expf(-x)); }

__device__ __forceinline__ void f_stage(
    float (*aT)[FRTP], float (*wt)[FNT], int row0, int k0,
    const float* a1g, int a1pitch, const int* gidx, const float* a1l, int a1lp, int K1,
    const float* a2g, int a2pitch, const float* a2l, int a2lp, int K2,
    const float* wa, int wap, int KW1, const float* wb, int wbp,
    int ncols, int tid)
{
    const int Ktot = K1 + K2;
    {
        const int kk = tid & 15, k = k0 + kk;
        #pragma unroll
        for (int h = 0; h < 2; ++h) {
            const int r = (tid >> 4) + h * 16;
            float v = 0.0f;
            if (k < K1) {
                if (a1l) v = a1l[r * a1lp + k];
                else {
                    const long rb = gidx ? (long)gidx[row0 + r] * a1pitch : (long)(row0 + r) * a1pitch;
                    v = a1g[rb + k];
                }
            } else if (k < Ktot) {
                if (a2l) v = a2l[r * a2lp + (k - K1)];
                else     v = a2g[(long)(row0 + r) * a2pitch + (k - K1)];
            }
            aT[kk][r] = v;
        }
    }
    {
        const int col = tid;
        #pragma unroll
        for (int kk = 0; kk < FBK; ++kk) {
            const int k = k0 + kk; float v = 0.0f;
            if (col < ncols && k < Ktot) {
                if (k < KW1) v = wa[(long)col * wap + k];
                else         v = wb[(long)col * wbp + (k - KW1)];
            }
            wt[kk][col] = v;
        }
    }
}
__device__ __forceinline__ void f_gemm(
    float (*aT)[FRTP], float (*wt)[FNT], float acc[8][4], int row0,
    const float* a1g, int a1p, const int* gidx, const float* a1l, int a1lp, int K1,
    const float* a2g, int a2p, const float* a2l, int a2lp, int K2,
    const float* wa, int wap, int KW1, const float* wb, int wbp,
    int ncols, int tid, int tr, int tc)
{
    #pragma unroll
    for (int j = 0; j < 8; ++j)
        #pragma unroll
        for (int i = 0; i < 4; ++i) acc[j][i] = 0.0f;
    const int Ktot = K1 + K2;
    for (int k0 = 0; k0 < Ktot; k0 += FBK) {
        __syncthreads();
        f_stage(aT, wt, row0, k0, a1g, a1p, gidx, a1l, a1lp, K1, a2g, a2p, a2l, a2lp, K2,
                wa, wap, KW1, wb, wbp, ncols, tid);
        __syncthreads();
        #pragma unroll
        for (int kk = 0; kk < FBK; ++kk) {
            const float w0 = wt[kk][tc*4+0], w1 = wt[kk][tc*4+1], w2 = wt[kk][tc*4+2], w3 = wt[kk][tc*4+3];
            #pragma unroll
            for (int j = 0; j < 8; ++j) {
                const float a = aT[kk][tr*8+j];
                acc[j][0] = fmaf(a, w0, acc[j][0]); acc[j][1] = fmaf(a, w1, acc[j][1]);
                acc[j][2] = fmaf(a, w2, acc[j][2]); acc[j][3] = fmaf(a, w3, acc[j][3]);
            }
        }
    }
}
__global__ __launch_bounds__(256)
void fused_fp32(const int* tok, const float* chc, const float* chh, const float* emb,
                const float* p1w, const float* p1b, const float* p2w, const float* p2b,
                const float* ixw, const float* ixb, const float* ihw, const float* ihb,
                const float* fxw, const float* fxb, const float* fhw, const float* fhb,
                const float* uxw, const float* uxb, const float* uhw, const float* uhb,
                const float* oxw, const float* oxb, const float* ohw, const float* ohb,
                const float* fc2w, const float* fc2b, float* out)
{
    __shared__ float aT[FBK][FRTP]; __shared__ float wt[FBK][FNT]; __shared__ float buf[FRT][FBUFP];
    const int tid = threadIdx.x, tr = tid >> 6, tc = tid & 63, c0 = tc * 4;
    const int row0 = blockIdx.x * FRT;
    float acc[8][4];
    f_gemm(aT, wt, acc, row0, chh, 800, nullptr, nullptr, 0, 600, nullptr,0,nullptr,0,0, p1w,600,600,nullptr,0, DDIM, tid,tr,tc);
    if (c0 < DDIM) { const float4 b = *(const float4*)&p1b[c0];
        #pragma unroll
        for (int j=0;j<8;++j){int r=tr*8+j; buf[r][c0]=fmaxf(acc[j][0]+b.x,0.f); buf[r][c0+1]=fmaxf(acc[j][1]+b.y,0.f); buf[r][c0+2]=fmaxf(acc[j][2]+b.z,0.f); buf[r][c0+3]=fmaxf(acc[j][3]+b.w,0.f);} }
    f_gemm(aT, wt, acc, row0, nullptr,0,nullptr,&buf[0][0],FBUFP,200, chh+600,800,nullptr,0,200, p2w,400,400,nullptr,0, DDIM, tid,tr,tc);
    if (c0 < DDIM) { const float4 b = *(const float4*)&p2b[c0];
        #pragma unroll
        for (int j=0;j<8;++j){int r=tr*8+j; buf[r][c0]=fmaxf(acc[j][0]+b.x,0.f); buf[r][c0+1]=fmaxf(acc[j][1]+b.y,0.f); buf[r][c0+2]=fmaxf(acc[j][2]+b.z,0.f); buf[r][c0+3]=fmaxf(acc[j][3]+b.w,0.f);} }
    f_gemm(aT, wt, acc, row0, emb, DDIM, tok, nullptr,0,200, nullptr,0,nullptr,0,0, fxw,200,200,nullptr,0, DDIM, tid,tr,tc);
    float fxr[8][4];
    { float4 b = make_float4(0,0,0,0); if (c0<DDIM) b = *(const float4*)&fxb[c0];
      #pragma unroll
      for (int j=0;j<8;++j){fxr[j][0]=acc[j][0]+b.x;fxr[j][1]=acc[j][1]+b.y;fxr[j][2]=acc[j][2]+b.z;fxr[j][3]=acc[j][3]+b.w;} }
    float csum[8][4];
    #pragma unroll
    for (int j=0;j<8;++j)
        #pragma unroll
        for (int i=0;i<4;++i) csum[j][i]=0.f;
    for (int cc_=0; cc_<4; ++cc_) {
        f_gemm(aT, wt, acc, row0, chh+cc_*200,800,nullptr,nullptr,0,200, nullptr,0,nullptr,0,0, fhw,200,200,nullptr,0, DDIM, tid,tr,tc);
        if (c0 < DDIM) { const float4 b = *(const float4*)&fhb[c0];
            #pragma unroll
            for (int j=0;j<8;++j){ const long r=row0+tr*8+j; const float4 cv=*(const float4*)&chc[r*800+cc_*200+c0];
                csum[j][0]+=sgm_f(acc[j][0]+b.x+fxr[j][0])*cv.x; csum[j][1]+=sgm_f(acc[j][1]+b.y+fxr[j][1])*cv.y;
                csum[j][2]+=sgm_f(acc[j][2]+b.z+fxr[j][2])*cv.z; csum[j][3]+=sgm_f(acc[j][3]+b.w+fxr[j][3])*cv.w; } }
    }
    f_gemm(aT, wt, acc, row0, emb, DDIM, tok, nullptr,0,200, nullptr,0,&buf[0][0],FBUFP,200, ixw,200,200,ihw,200, DDIM, tid,tr,tc);
    float gi[8][4];
    { float4 b1=make_float4(0,0,0,0),b2=b1; if(c0<DDIM){b1=*(const float4*)&ixb[c0];b2=*(const float4*)&ihb[c0];}
      #pragma unroll
      for(int j=0;j<8;++j){gi[j][0]=sgm_f(acc[j][0]+b1.x+b2.x);gi[j][1]=sgm_f(acc[j][1]+b1.y+b2.y);gi[j][2]=sgm_f(acc[j][2]+b1.z+b2.z);gi[j][3]=sgm_f(acc[j][3]+b1.w+b2.w);} }
    f_gemm(aT, wt, acc, row0, emb, DDIM, tok, nullptr,0,200, nullptr,0,&buf[0][0],FBUFP,200, uxw,200,200,uhw,200, DDIM, tid,tr,tc);
    float cval[8][4];
    { float4 b1=make_float4(0,0,0,0),b2=b1; if(c0<DDIM){b1=*(const float4*)&uxb[c0];b2=*(const float4*)&uhb[c0];}
      #pragma unroll
      for(int j=0;j<8;++j){cval[j][0]=gi[j][0]*tanhf(acc[j][0]+b1.x+b2.x)+csum[j][0];cval[j][1]=gi[j][1]*tanhf(acc[j][1]+b1.y+b2.y)+csum[j][1];
                           cval[j][2]=gi[j][2]*tanhf(acc[j][2]+b1.z+b2.z)+csum[j][2];cval[j][3]=gi[j][3]*tanhf(acc[j][3]+b1.w+b2.w)+csum[j][3];} }
    f_gemm(aT, wt, acc, row0, emb, DDIM, tok, nullptr,0,200, nullptr,0,&buf[0][0],FBUFP,200, oxw,200,200,ohw,200, DDIM, tid,tr,tc);
    if (c0 < DDIM) { const float4 b1=*(const float4*)&oxb[c0], b2=*(const float4*)&ohb[c0];
        #pragma unroll
        for(int j=0;j<8;++j){int r=tr*8+j;
            buf[r][c0]=sgm_f(acc[j][0]+b1.x+b2.x)*tanhf(cval[j][0]); buf[r][c0+1]=sgm_f(acc[j][1]+b1.y+b2.y)*tanhf(cval[j][1]);
            buf[r][c0+2]=sgm_f(acc[j][2]+b1.z+b2.z)*tanhf(cval[j][2]); buf[r][c0+3]=sgm_f(acc[j][3]+b1.w+b2.w)*tanhf(cval[j][3]);} }
    f_gemm(aT, wt, acc, row0, nullptr,0,nullptr,&buf[0][0],FBUFP,200, nullptr,0,nullptr,0,0, fc2w,200,200,nullptr,0, NCLS, tid,tr,tc);
    #pragma unroll
    for (int j=0;j<8;++j){ const long r=row0+tr*8+j;
        #pragma unroll
        for (int i=0;i<4;++i){ const int col=c0+i; if (col<NCLS) out[r*NCLS+col]=acc[j][i]+fc2b[col]; } }
}

// ================= launch =================
extern "C" void kernel_launch(void* const* d_in, const int* in_sizes, int n_in,
                              void* d_out, int out_size, void* d_ws, size_t ws_size,
                              hipStream_t stream)
{
    const int*   tok  = (const int*)  d_in[0];
    const float* chc  = (const float*)d_in[1];
    const float* chh  = (const float*)d_in[2];
    const float* emb  = (const float*)d_in[3];
    const float* p1w  = (const float*)d_in[4];
    const float* p1b  = (const float*)d_in[5];
    const float* p2w  = (const float*)d_in[6];
    const float* p2b  = (const float*)d_in[7];
    const float* ixw  = (const float*)d_in[8];
    const float* ixb  = (const float*)d_in[9];
    const float* ihw  = (const float*)d_in[10];
    const float* ihb  = (const float*)d_in[11];
    const float* fxw  = (const float*)d_in[12];
    const float* fxb  = (const float*)d_in[13];
    const float* fhw  = (const float*)d_in[14];
    const float* fhb  = (const float*)d_in[15];
    const float* uxw  = (const float*)d_in[16];
    const float* uxb  = (const float*)d_in[17];
    const float* uhw  = (const float*)d_in[18];
    const float* uhb  = (const float*)d_in[19];
    const float* oxw  = (const float*)d_in[20];
    const float* oxb  = (const float*)d_in[21];
    const float* ohw  = (const float*)d_in[22];
    const float* ohb  = (const float*)d_in[23];
    const float* fc2w = (const float*)d_in[24];
    const float* fc2b = (const float*)d_in[25];
    float* out = (float*)d_out;

    if (ws_size >= W_TOTAL_BYTES) {
        short* ws = (short*)d_ws;
        hipLaunchKernelGGL(wprep, dim3((W_TOTAL_ELEMS + 255) / 256), dim3(256), 0, stream,
                           p1w, p2w, fxw, fhw, ixw, ihw, uxw, uhw, oxw, ohw, fc2w, ws);
        hipLaunchKernelGGL(fused_v8, dim3((NNODES + R - 1) / R), dim3(512), 0, stream,
                           tok, chc, chh, emb,
                           p1b, p2b, ixb, ihb, fxb, fhb, uxb, uhb, oxb, ohb, fc2b,
                           ws, out);
    } else {
        hipLaunchKernelGGL(fused_fp32, dim3(NNODES / FRT), dim3(256), 0, stream,
                           tok, chc, chh, emb, p1w, p1b, p2w, p2b,
                           ixw, ixb, ihw, ihb, fxw, fxb, fhw, fhb,
                           uxw, uxb, uhw, uhb, oxw, oxb, ohw, ohb, fc2w, fc2b, out);
    }
}